// Round 8
// baseline (98.340 us; speedup 1.0000x reference)
//
#include <hip/hip_runtime.h>
#include <hip/hip_bf16.h>

// Problem constants (setup_inputs: B=64, S=1024, H=128, A=8, CTX_WIN=5, PAD=2)
#define S_DIM 1024
#define H_DIM 128
#define A_DIM 8
#define W_WIN 5

typedef unsigned int uint;
typedef unsigned short ushort;
typedef __attribute__((ext_vector_type(8))) short short8;   // 8 bf16 = 4 VGPRs
typedef __attribute__((ext_vector_type(4))) float f32x4;

union U128 { uint4 u; short8 s; };

__device__ __forceinline__ ushort f2bf(float f) {
    uint u = __float_as_uint(f);
    uint r = (u + 0x7fffu + ((u >> 16) & 1u)) >> 16;   // round-to-nearest-even
    return (ushort)r;
}

// ---------------------------------------------------------------------------
// K1: Gt[n][k] (bf16, 16 x 640 dense), k = w*128 + h.
//   n<8:  Gt[a][w*128+h] = sum_f P[a,h,f] * E[a,f,w]
//   n>=8: zeros (aspect padding for the 16-wide MFMA N dim)
// ---------------------------------------------------------------------------
__global__ __launch_bounds__(128) void k_g(const float* __restrict__ P,
                                           const float* __restrict__ We,
                                           ushort* __restrict__ Gt) {
    const int a = blockIdx.x;        // 0..15
    const int h = threadIdx.x;       // 0..127
    if (a >= A_DIM) {
        for (int i = h; i < W_WIN * H_DIM; i += 128) Gt[a * (W_WIN * H_DIM) + i] = 0;
        return;
    }
    __shared__ float Es[H_DIM * W_WIN];
    for (int i = h; i < H_DIM * W_WIN; i += 128) Es[i] = We[a * (H_DIM * W_WIN) + i];
    __syncthreads();

    const float* Pr = P + ((size_t)a * H_DIM + h) * H_DIM;
    float acc[W_WIN] = {0.f, 0.f, 0.f, 0.f, 0.f};
#pragma unroll 8
    for (int f = 0; f < H_DIM; f += 4) {
        float4 pv = *(const float4*)(Pr + f);
        float pj[4] = {pv.x, pv.y, pv.z, pv.w};
#pragma unroll
        for (int j = 0; j < 4; ++j) {
            const float p = pj[j];
            const float* e = &Es[(f + j) * W_WIN];
#pragma unroll
            for (int w = 0; w < W_WIN; ++w) acc[w] += p * e[w];
        }
    }
#pragma unroll
    for (int w = 0; w < W_WIN; ++w)
        Gt[a * (W_WIN * H_DIM) + w * H_DIM + h] = f2bf(acc[w]);
}

// ---------------------------------------------------------------------------
// K2: per (b, 64-s slice). LDS only ~20.4 KB (doc tile + e) -> 5 blocks/CU
// (VGPR-bound), Gt read directly from global (20 KB, L1-resident).
//  B: score[a][s] = sum_{w,h} doc[s+w-2,h]*G[a,wh]   (MFMA, M=64 s,N=16 a,K=640)
//  C: e = exp(score) -> escore (global bf16), el (LDS bf16), Zw
//  D: numPart[slice][a][h] = sum_s e[a][s]*doc[s][h] (MFMA, M=a,N=h,K=64)
//  E: pure stores of per-slice partials (no atomics, no fences).
// Softmax shift m=0 is exact here (|score| < ~0.1, softmax shift-invariant).
// ---------------------------------------------------------------------------
#define CS 64
#define RROWS (CS + 4)        // 68
#define EPITCH 88             // el pitch (176 B: 16B-aligned, 2-way banks)
__global__ __launch_bounds__(256) void k_scores(const float* __restrict__ Din,
                                                const ushort* __restrict__ Gt,
                                                ushort* __restrict__ escore,
                                                float* __restrict__ numPart,
                                                float* __restrict__ Zpart) {
    __shared__ uint4 Dl[RROWS * 16];      // 17408 B bf16 doc tile, XOR swizzle
    __shared__ ushort el[16 * EPITCH];    // 2816 B  e as bf16, [a][s]
    __shared__ float Zw[32];
    const int b   = blockIdx.y;
    const int slc = blockIdx.x;           // 0..15
    const int s0  = slc * CS;
    const int t   = threadIdx.x;
    const float* Db = Din + (size_t)b * S_DIM * H_DIM;

    // --- stage doc rows [s0-2, s0+CS+2), bf16, 16B-chunk XOR swizzle ---
    for (int i = t; i < RROWS * 16; i += 256) {
        const int r = i >> 4, c = i & 15;
        const int gs = s0 - 2 + r;
        float4 va = make_float4(0.f, 0.f, 0.f, 0.f), vb = va;
        if (gs >= 0 && gs < S_DIM) {
            const float* p = Db + (size_t)gs * H_DIM + c * 8;
            va = ((const float4*)p)[0];
            vb = ((const float4*)p)[1];
        }
        uint4 q;
        q.x = (uint)f2bf(va.x) | ((uint)f2bf(va.y) << 16);
        q.y = (uint)f2bf(va.z) | ((uint)f2bf(va.w) << 16);
        q.z = (uint)f2bf(vb.x) | ((uint)f2bf(vb.y) << 16);
        q.w = (uint)f2bf(vb.z) | ((uint)f2bf(vb.w) << 16);
        Dl[r * 16 + (c ^ (r & 15))] = q;
    }
    __syncthreads();

    const int lane = t & 63;
    const int wv   = t >> 6;          // wave id 0..3 -> m-tile (16 s-rows)
    const int lm   = lane & 15;
    const int lq   = lane >> 4;

    // ---- Phase B: score MFMA; B-frags straight from global (L1-hot) ----
    const uint4* Gg = (const uint4*)(Gt + lm * (W_WIN * H_DIM));   // row n=lm
    f32x4 acc0 = {0.f, 0.f, 0.f, 0.f};
#pragma unroll
    for (int kk = 0; kk < 20; ++kk) {
        const int w = kk >> 2;
        const int r0 = wv * 16 + lm + w;
        const int cidx = (kk & 3) * 4 + lq;
        U128 av, bv;
        bv.u = Gg[kk * 4 + lq];                        // Gt[lm][kk*32+lq*8 ..]
        av.u = Dl[r0 * 16 + (cidx ^ (r0 & 15))];
        acc0 = __builtin_amdgcn_mfma_f32_16x16x32_bf16(av.s, bv.s, acc0, 0, 0, 0);
    }

    // ---- Phase C: e = exp(score); escore bf16, el LDS, Z wave-partials ----
    // C layout: col(a)=lm, rows s = wv*16 + lq*4 + r
    float4 e0;
    e0.x = __expf(acc0.x); e0.y = __expf(acc0.y); e0.z = __expf(acc0.z); e0.w = __expf(acc0.w);
    uint2 d0;
    d0.x = (uint)f2bf(e0.x) | ((uint)f2bf(e0.y) << 16);
    d0.y = (uint)f2bf(e0.z) | ((uint)f2bf(e0.w) << 16);
    const int sb = wv * 16 + lq * 4;
    if (lm < A_DIM)
        *(uint2*)(escore + (((size_t)b * A_DIM + lm) << 10) + s0 + sb) = d0;
    *(uint2*)(&el[lm * EPITCH + sb]) = d0;   // rows a>=8 hold exp(0)=1: unused

    float es = e0.x + e0.y + e0.z + e0.w;
    es += __shfl_xor(es, 16);
    es += __shfl_xor(es, 32);
    if (lq == 0 && lm < A_DIM) Zw[wv * 8 + lm] = es;
    __syncthreads();

    // ---- Phase D: numerator MFMA  C[m=a][n=h], K=s=64 ----
    const ushort* Dls = (const ushort*)Dl;
    U128 afr[2];
#pragma unroll
    for (int kk = 0; kk < 2; ++kk)
        afr[kk].u = *(const uint4*)(&el[lm * EPITCH + kk * 32 + lq * 8]);

    f32x4 accN[2] = {{0.f,0.f,0.f,0.f},{0.f,0.f,0.f,0.f}};
#pragma unroll
    for (int nt = 0; nt < 2; ++nt) {
        const int h  = wv * 32 + nt * 16 + lm;
        const int ch = h >> 3, hw = h & 7;
#pragma unroll
        for (int kk = 0; kk < 2; ++kk) {
            uint p[4];
#pragma unroll
            for (int jj = 0; jj < 4; ++jj) {
                const int sj = kk * 32 + lq * 8 + jj * 2;
                const int ra = sj + 2, rb = sj + 3;   // +2 halo offset
                const uint lo = Dls[(ra * 16 + (ch ^ (ra & 15))) * 8 + hw];
                const uint hi = Dls[(rb * 16 + (ch ^ (rb & 15))) * 8 + hw];
                p[jj] = lo | (hi << 16);
            }
            U128 bfr; bfr.u = make_uint4(p[0], p[1], p[2], p[3]);
            accN[nt] = __builtin_amdgcn_mfma_f32_16x16x32_bf16(afr[kk].s, bfr.s, accN[nt], 0, 0, 0);
        }
    }

    // ---- Phase E: per-slice partials, pure stores ----
    if (lq < 2) {   // C rows m = lq*4+r = aspect 0..7
#pragma unroll
        for (int nt = 0; nt < 2; ++nt) {
            const int h = wv * 32 + nt * 16 + lm;
#pragma unroll
            for (int r = 0; r < 4; ++r)
                numPart[(((size_t)(b * 16 + slc) * 8) + lq * 4 + r) * H_DIM + h] = accN[nt][r];
        }
    }
    if (t < A_DIM)
        Zpart[(b * 16 + slc) * 8 + t] = Zw[t] + Zw[8 + t] + Zw[16 + t] + Zw[24 + t];
}

// ---------------------------------------------------------------------------
// K3: per (b,a): Z = sum Zpart; attn = escore/Z -> d_out;
//     wsum[h] = sum numPart / Z; rep[b,a,f] = sum_h wsum[h]*P[a,h,f]
// ---------------------------------------------------------------------------
__global__ __launch_bounds__(128) void k_final(const ushort* __restrict__ escore,
                                               const float* __restrict__ numPart,
                                               const float* __restrict__ Zpart,
                                               const float* __restrict__ P,
                                               float* __restrict__ attn,
                                               float* __restrict__ rep) {
    __shared__ float ws[H_DIM];
    const int ba = blockIdx.x;                // b*8 + a
    const int b = ba >> 3, a = ba & 7;
    const int t = threadIdx.x;

    float Zs = 0.f;
#pragma unroll
    for (int k = 0; k < 16; ++k) Zs += Zpart[(b * 16 + k) * 8 + a];
    const float rz = 1.0f / Zs;

    float s = 0.f;
#pragma unroll
    for (int k = 0; k < 16; ++k)
        s += numPart[(((size_t)(b * 16 + k) * 8) + a) * H_DIM + t];
    ws[t] = s * rz;

    const ushort* ep = escore + (size_t)ba * S_DIM;
    float* ap = attn + (size_t)ba * S_DIM;
#pragma unroll
    for (int i = 0; i < 2; ++i) {
        uint2 q = *(const uint2*)(ep + i * 512 + t * 4);
        float4 v;
        v.x = __uint_as_float(q.x << 16) * rz;
        v.y = __uint_as_float(q.x & 0xffff0000u) * rz;
        v.z = __uint_as_float(q.y << 16) * rz;
        v.w = __uint_as_float(q.y & 0xffff0000u) * rz;
        *(float4*)(ap + i * 512 + t * 4) = v;
    }
    __syncthreads();

    const float* Pa = P + (size_t)a * H_DIM * H_DIM + t;
    float acc = 0.f;
#pragma unroll 32
    for (int hh = 0; hh < H_DIM; ++hh)
        acc += ws[hh] * Pa[(size_t)hh * H_DIM];
    rep[(size_t)ba * H_DIM + t] = acc;
}

// ---------------------------------------------------------------------------
extern "C" void kernel_launch(void* const* d_in, const int* in_sizes, int n_in,
                              void* d_out, int out_size, void* d_ws, size_t ws_size,
                              hipStream_t stream) {
    const float* docIn = (const float*)d_in[0];   // (B, S, H) fp32
    const float* We    = (const float*)d_in[1];   // (A, 5*H)  fp32
    const float* P     = (const float*)d_in[2];   // (A, H, H) fp32
    float* out = (float*)d_out;                   // [B*A*S attn | B*A*H rep]

    const int B = in_sizes[0] / (S_DIM * H_DIM);  // 64

    ushort* Gt     = (ushort*)d_ws;                                   // 20 KB
    ushort* escore = (ushort*)((char*)d_ws + 32768);                  // B*A*S bf16 = 1 MB
    float* numPart = (float*)((char*)d_ws + 32768 +
                              (size_t)B * A_DIM * S_DIM * 2);         // B*16*8*H
    float* Zpart   = numPart + (size_t)B * 16 * 8 * H_DIM;            // B*16*8

    k_g<<<16, 128, 0, stream>>>(P, We, Gt);
    k_scores<<<dim3(S_DIM / CS, B), 256, 0, stream>>>(docIn, Gt, escore, numPart, Zpart);
    k_final<<<B * A_DIM, 128, 0, stream>>>(escore, numPart, Zpart, P, out,
                                           out + (size_t)B * A_DIM * S_DIM);
}

// Round 9
// 91.792 us; speedup vs baseline: 1.0713x; 1.0713x over previous
//
#include <hip/hip_runtime.h>
#include <hip/hip_bf16.h>

// Problem constants (setup_inputs: B=64, S=1024, H=128, A=8, CTX_WIN=5, PAD=2)
#define S_DIM 1024
#define H_DIM 128
#define A_DIM 8
#define W_WIN 5

typedef unsigned int uint;
typedef unsigned short ushort;
typedef __attribute__((ext_vector_type(8))) short short8;   // 8 bf16 = 4 VGPRs
typedef __attribute__((ext_vector_type(4))) float f32x4;

union U128 { uint4 u; short8 s; };

__device__ __forceinline__ ushort f2bf(float f) {
    uint u = __float_as_uint(f);
    uint r = (u + 0x7fffu + ((u >> 16) & 1u)) >> 16;   // round-to-nearest-even
    return (ushort)r;
}

// ---------------------------------------------------------------------------
// K1: Gt[n][k] (bf16, 16 x 640 dense), k = w*128 + h.
//   n<8:  Gt[a][w*128+h] = sum_f P[a,h,f] * E[a,f,w]
//   n>=8: zeros (aspect padding; K2 only reads rows 0..7 + synthesizes zeros)
// ---------------------------------------------------------------------------
__global__ __launch_bounds__(128) void k_g(const float* __restrict__ P,
                                           const float* __restrict__ We,
                                           ushort* __restrict__ Gt) {
    const int a = blockIdx.x;        // 0..15
    const int h = threadIdx.x;       // 0..127
    if (a >= A_DIM) {
        for (int i = h; i < W_WIN * H_DIM; i += 128) Gt[a * (W_WIN * H_DIM) + i] = 0;
        return;
    }
    __shared__ float Es[H_DIM * W_WIN];
    for (int i = h; i < H_DIM * W_WIN; i += 128) Es[i] = We[a * (H_DIM * W_WIN) + i];
    __syncthreads();

    const float* Pr = P + ((size_t)a * H_DIM + h) * H_DIM;
    float acc[W_WIN] = {0.f, 0.f, 0.f, 0.f, 0.f};
#pragma unroll 8
    for (int f = 0; f < H_DIM; f += 4) {
        float4 pv = *(const float4*)(Pr + f);
        float pj[4] = {pv.x, pv.y, pv.z, pv.w};
#pragma unroll
        for (int j = 0; j < 4; ++j) {
            const float p = pj[j];
            const float* e = &Es[(f + j) * W_WIN];
#pragma unroll
            for (int w = 0; w < W_WIN; ++w) acc[w] += p * e[w];
        }
    }
#pragma unroll
    for (int w = 0; w < W_WIN; ++w)
        Gt[a * (W_WIN * H_DIM) + w * H_DIM + h] = f2bf(acc[w]);
}

// ---------------------------------------------------------------------------
// K2: per (b, 64-s slice). LDS 31.9 KB (doc tile + 9-row Gl + e) -> 5 blocks/CU
// (20 waves/CU), inner loop LDS-only (no vmcnt in K-loop — R8 lesson).
//  B: score[a][s] = sum_{w,h} doc[s+w-2,h]*G[a,wh]   (MFMA, M=64 s,N=16 a,K=640)
//  C: e = exp(score) -> escore (global bf16), el (LDS bf16), Zw
//  D: numPart[slice][a][h] = sum_s e[a][s]*doc[s][h] (MFMA, M=a,N=h,K=64)
//  E: pure stores of per-slice partials (no atomics, no fences).
// Softmax shift m=0 is exact here (|score| < ~0.1, softmax shift-invariant).
// ---------------------------------------------------------------------------
#define CS 64
#define RROWS (CS + 4)        // 68
#define EPITCH 88             // el pitch (176 B: 16B-aligned, 2-way banks)
__global__ __launch_bounds__(256) void k_scores(const float* __restrict__ Din,
                                                const ushort* __restrict__ Gt,
                                                ushort* __restrict__ escore,
                                                float* __restrict__ numPart,
                                                float* __restrict__ Zpart) {
    __shared__ uint4 Dl[RROWS * 16];      // 17408 B bf16 doc tile, XOR swizzle
    __shared__ uint4 Gl[9 * 80];          // 11520 B: 8 aspect rows + zero row
    __shared__ ushort el[16 * EPITCH];    // 2816 B  e as bf16, [a][s]
    __shared__ float Zw[32];
    const int b   = blockIdx.y;
    const int slc = blockIdx.x;           // 0..15
    const int s0  = slc * CS;
    const int t   = threadIdx.x;
    const float* Db = Din + (size_t)b * S_DIM * H_DIM;

    // --- stage doc rows [s0-2, s0+CS+2), bf16, 16B-chunk XOR swizzle ---
    for (int i = t; i < RROWS * 16; i += 256) {
        const int r = i >> 4, c = i & 15;
        const int gs = s0 - 2 + r;
        float4 va = make_float4(0.f, 0.f, 0.f, 0.f), vb = va;
        if (gs >= 0 && gs < S_DIM) {
            const float* p = Db + (size_t)gs * H_DIM + c * 8;
            va = ((const float4*)p)[0];
            vb = ((const float4*)p)[1];
        }
        uint4 q;
        q.x = (uint)f2bf(va.x) | ((uint)f2bf(va.y) << 16);
        q.y = (uint)f2bf(va.z) | ((uint)f2bf(va.w) << 16);
        q.z = (uint)f2bf(vb.x) | ((uint)f2bf(vb.y) << 16);
        q.w = (uint)f2bf(vb.z) | ((uint)f2bf(vb.w) << 16);
        Dl[r * 16 + (c ^ (r & 15))] = q;
    }
    // --- stage Gl: rows 0..7 = Gt aspects, row 8 = zeros; chunk XOR swizzle ---
    {
        const uint4* Gg = (const uint4*)Gt;
        for (int i = t; i < 9 * 80; i += 256) {
            const int n = i / 80, c = i - n * 80;
            uint4 v = make_uint4(0u, 0u, 0u, 0u);
            if (n < 8) v = Gg[n * 80 + c];
            Gl[n * 80 + ((c & ~15) | ((c & 15) ^ n))] = v;
        }
    }
    __syncthreads();

    const int lane = t & 63;
    const int wv   = t >> 6;          // wave id 0..3 -> m-tile (16 s-rows)
    const int lm   = lane & 15;
    const int lq   = lane >> 4;
    const int gr   = (lm < 8) ? lm : 8;   // Gl row (8 = shared zero row)

    // ---- Phase B: score MFMA (LDS-only inner loop) ----
    f32x4 acc0 = {0.f, 0.f, 0.f, 0.f};
#pragma unroll
    for (int kk = 0; kk < 20; ++kk) {
        const int w = kk >> 2;
        const int r0 = wv * 16 + lm + w;
        const int cidx = (kk & 3) * 4 + lq;
        const int gc = kk * 4 + lq;
        U128 av, bv;
        bv.u = Gl[gr * 80 + ((gc & ~15) | ((gc & 15) ^ gr))];
        av.u = Dl[r0 * 16 + (cidx ^ (r0 & 15))];
        acc0 = __builtin_amdgcn_mfma_f32_16x16x32_bf16(av.s, bv.s, acc0, 0, 0, 0);
    }

    // ---- Phase C: e = exp(score); escore bf16, el LDS, Z wave-partials ----
    // C layout: col(a)=lm, rows s = wv*16 + lq*4 + r
    float4 e0;
    e0.x = __expf(acc0.x); e0.y = __expf(acc0.y); e0.z = __expf(acc0.z); e0.w = __expf(acc0.w);
    uint2 d0;
    d0.x = (uint)f2bf(e0.x) | ((uint)f2bf(e0.y) << 16);
    d0.y = (uint)f2bf(e0.z) | ((uint)f2bf(e0.w) << 16);
    const int sb = wv * 16 + lq * 4;
    if (lm < A_DIM)
        *(uint2*)(escore + (((size_t)b * A_DIM + lm) << 10) + s0 + sb) = d0;
    *(uint2*)(&el[lm * EPITCH + sb]) = d0;   // rows a>=8 hold exp(0)=1: unused

    float es = e0.x + e0.y + e0.z + e0.w;
    es += __shfl_xor(es, 16);
    es += __shfl_xor(es, 32);
    if (lq == 0 && lm < A_DIM) Zw[wv * 8 + lm] = es;
    __syncthreads();

    // ---- Phase D: numerator MFMA  C[m=a][n=h], K=s=64 ----
    const ushort* Dls = (const ushort*)Dl;
    U128 afr[2];
#pragma unroll
    for (int kk = 0; kk < 2; ++kk)
        afr[kk].u = *(const uint4*)(&el[lm * EPITCH + kk * 32 + lq * 8]);

    f32x4 accN[2] = {{0.f,0.f,0.f,0.f},{0.f,0.f,0.f,0.f}};
#pragma unroll
    for (int nt = 0; nt < 2; ++nt) {
        const int h  = wv * 32 + nt * 16 + lm;
        const int ch = h >> 3, hw = h & 7;
#pragma unroll
        for (int kk = 0; kk < 2; ++kk) {
            uint p[4];
#pragma unroll
            for (int jj = 0; jj < 4; ++jj) {
                const int sj = kk * 32 + lq * 8 + jj * 2;
                const int ra = sj + 2, rb = sj + 3;   // +2 halo offset
                const uint lo = Dls[(ra * 16 + (ch ^ (ra & 15))) * 8 + hw];
                const uint hi = Dls[(rb * 16 + (ch ^ (rb & 15))) * 8 + hw];
                p[jj] = lo | (hi << 16);
            }
            U128 bfr; bfr.u = make_uint4(p[0], p[1], p[2], p[3]);
            accN[nt] = __builtin_amdgcn_mfma_f32_16x16x32_bf16(afr[kk].s, bfr.s, accN[nt], 0, 0, 0);
        }
    }

    // ---- Phase E: per-slice partials, pure stores ----
    if (lq < 2) {   // C rows m = lq*4+r = aspect 0..7
#pragma unroll
        for (int nt = 0; nt < 2; ++nt) {
            const int h = wv * 32 + nt * 16 + lm;
#pragma unroll
            for (int r = 0; r < 4; ++r)
                numPart[(((size_t)(b * 16 + slc) * 8) + lq * 4 + r) * H_DIM + h] = accN[nt][r];
        }
    }
    if (t < A_DIM)
        Zpart[(b * 16 + slc) * 8 + t] = Zw[t] + Zw[8 + t] + Zw[16 + t] + Zw[24 + t];
}

// ---------------------------------------------------------------------------
// K3: per (b,a): Z = sum Zpart; attn = escore/Z -> d_out;
//     wsum[h] = sum numPart / Z; rep[b,a,f] = sum_h wsum[h]*P[a,h,f]
// ---------------------------------------------------------------------------
__global__ __launch_bounds__(128) void k_final(const ushort* __restrict__ escore,
                                               const float* __restrict__ numPart,
                                               const float* __restrict__ Zpart,
                                               const float* __restrict__ P,
                                               float* __restrict__ attn,
                                               float* __restrict__ rep) {
    __shared__ float ws[H_DIM];
    const int ba = blockIdx.x;                // b*8 + a
    const int b = ba >> 3, a = ba & 7;
    const int t = threadIdx.x;

    float Zs = 0.f;
#pragma unroll
    for (int k = 0; k < 16; ++k) Zs += Zpart[(b * 16 + k) * 8 + a];
    const float rz = 1.0f / Zs;

    float s = 0.f;
#pragma unroll
    for (int k = 0; k < 16; ++k)
        s += numPart[(((size_t)(b * 16 + k) * 8) + a) * H_DIM + t];
    ws[t] = s * rz;

    const ushort* ep = escore + (size_t)ba * S_DIM;
    float* ap = attn + (size_t)ba * S_DIM;
#pragma unroll
    for (int i = 0; i < 2; ++i) {
        uint2 q = *(const uint2*)(ep + i * 512 + t * 4);
        float4 v;
        v.x = __uint_as_float(q.x << 16) * rz;
        v.y = __uint_as_float(q.x & 0xffff0000u) * rz;
        v.z = __uint_as_float(q.y << 16) * rz;
        v.w = __uint_as_float(q.y & 0xffff0000u) * rz;
        *(float4*)(ap + i * 512 + t * 4) = v;
    }
    __syncthreads();

    const float* Pa = P + (size_t)a * H_DIM * H_DIM + t;
    float acc = 0.f;
#pragma unroll 32
    for (int hh = 0; hh < H_DIM; ++hh)
        acc += ws[hh] * Pa[(size_t)hh * H_DIM];
    rep[(size_t)ba * H_DIM + t] = acc;
}

// ---------------------------------------------------------------------------
extern "C" void kernel_launch(void* const* d_in, const int* in_sizes, int n_in,
                              void* d_out, int out_size, void* d_ws, size_t ws_size,
                              hipStream_t stream) {
    const float* docIn = (const float*)d_in[0];   // (B, S, H) fp32
    const float* We    = (const float*)d_in[1];   // (A, 5*H)  fp32
    const float* P     = (const float*)d_in[2];   // (A, H, H) fp32
    float* out = (float*)d_out;                   // [B*A*S attn | B*A*H rep]

    const int B = in_sizes[0] / (S_DIM * H_DIM);  // 64

    ushort* Gt     = (ushort*)d_ws;                                   // 20 KB
    ushort* escore = (ushort*)((char*)d_ws + 32768);                  // B*A*S bf16 = 1 MB
    float* numPart = (float*)((char*)d_ws + 32768 +
                              (size_t)B * A_DIM * S_DIM * 2);         // B*16*8*H
    float* Zpart   = numPart + (size_t)B * 16 * 8 * H_DIM;            // B*16*8

    k_g<<<16, 128, 0, stream>>>(P, We, Gt);
    k_scores<<<dim3(S_DIM / CS, B), 256, 0, stream>>>(docIn, Gt, escore, numPart, Zpart);
    k_final<<<B * A_DIM, 128, 0, stream>>>(escore, numPart, Zpart, P, out,
                                           out + (size_t)B * A_DIM * S_DIM);
}